// Round 1
// baseline (453.979 us; speedup 1.0000x reference)
//
#include <hip/hip_runtime.h>
#include <math.h>

// Problem constants (B=2, H=16, S=4096, D=64, W=256)
#define S_LEN 4096
#define DH    64
#define NHEAD 16
#define WI    256
#define NC    513        // 2W+1
#define TI    64         // query rows per block
#define CJ    96         // j-chunk width
#define NCH   6          // chunks: 6*96 = 576 = TI + 2*WI exactly
#define LSTR  68         // LDS row stride in floats (pad vs 64 to break bank stride)

// Virtual row v of "qr" for head-group p maps to x[b= p>>4][h= v&15][s= (p&15)*256 + (v>>4)][:]
// (this is exactly transpose(0,2,1,3).reshape(B*H, S, D) of the reference)

__global__ __launch_bounds__(256, 2)
void sliding_attn_kernel(const float* __restrict__ x, float* __restrict__ out) {
  const int t  = threadIdx.x;
  const int p  = blockIdx.y;          // 0..31
  const int i0 = blockIdx.x * TI;
  const int g  = t >> 4;              // row group 0..15 (4 rows each)
  const int l  = t & 15;              // lane within group
  const int b  = p >> 4;
  const int hh = p & 15;
  const int jb = i0 - WI;             // first j of the band span

  __shared__ float Qs[TI * LSTR];
  __shared__ float Ks[CJ * LSTR];

  // ---- stage Q tile (64 rows x 64 floats), coalesced float4 ----
#pragma unroll
  for (int k = 0; k < 4; ++k) {
    int qi  = t + k * 256;
    int row = qi >> 4;
    int dq  = qi & 15;
    int v   = i0 + row;                       // always in [0, S)
    int hx  = v & 15;
    int sx  = (hh << 8) + (v >> 4);
    const float4 val =
        *(const float4*)(x + (((b * NHEAD + hx) * S_LEN + sx) * DH + dq * 4));
    *(float4*)(Qs + row * LSTR + dq * 4) = val;
  }

  float acc[NCH][4][6];
#pragma unroll
  for (int m = 0; m < NCH; ++m)
#pragma unroll
    for (int r = 0; r < 4; ++r)
#pragma unroll
      for (int u = 0; u < 6; ++u) acc[m][r][u] = 0.f;

  // ---- main loop over 6 K-chunks of 96 rows ----
#pragma unroll
  for (int m = 0; m < NCH; ++m) {
    __syncthreads();   // previous chunk consumed (and Q stores visible on m=0)
#pragma unroll
    for (int k = 0; k < 6; ++k) {
      int qi  = t + k * 256;
      int rr  = qi >> 4;
      int dq  = qi & 15;
      int v   = jb + m * CJ + rr;
      float4 val = make_float4(0.f, 0.f, 0.f, 0.f);
      if (v >= 0 && v < S_LEN) {
        int hx = v & 15;
        int sx = (hh << 8) + (v >> 4);
        val = *(const float4*)(x + (((b * NHEAD + hx) * S_LEN + sx) * DH + dq * 4));
      }
      *(float4*)(Ks + rr * LSTR + dq * 4) = val;
    }
    __syncthreads();

#pragma unroll 2
    for (int dq = 0; dq < 16; ++dq) {
      float4 qv[4];
#pragma unroll
      for (int r = 0; r < 4; ++r)
        qv[r] = *(const float4*)(Qs + (g * 4 + r) * LSTR + dq * 4);
      float4 kv[6];
#pragma unroll
      for (int u = 0; u < 6; ++u)
        kv[u] = *(const float4*)(Ks + (l + 16 * u) * LSTR + dq * 4);
#pragma unroll
      for (int r = 0; r < 4; ++r)
#pragma unroll
        for (int u = 0; u < 6; ++u) {
          acc[m][r][u] = fmaf(qv[r].x, kv[u].x, acc[m][r][u]);
          acc[m][r][u] = fmaf(qv[r].y, kv[u].y, acc[m][r][u]);
          acc[m][r][u] = fmaf(qv[r].z, kv[u].z, acc[m][r][u]);
          acc[m][r][u] = fmaf(qv[r].w, kv[u].w, acc[m][r][u]);
        }
    }
  }

  // ---- softmax per row (16 lanes own one row's 576 slots) + write ----
#pragma unroll
  for (int r = 0; r < 4; ++r) {
    const int o = g * 4 + r;            // row offset in tile
    const int i = i0 + o;               // global virtual row

    float mx = -INFINITY;
#pragma unroll
    for (int m = 0; m < NCH; ++m)
#pragma unroll
      for (int u = 0; u < 6; ++u) {
        int cc = m * CJ + l + 16 * u;   // position within the 576-span
        int c  = cc - o;                // band column
        int j  = jb + cc;               // key row
        bool ok = (c >= 0) & (c <= 2 * WI) & (j >= 0) & (j < S_LEN);
        if (ok) mx = fmaxf(mx, acc[m][r][u]);
      }
#pragma unroll
    for (int off = 1; off < 16; off <<= 1)
      mx = fmaxf(mx, __shfl_xor(mx, off, 64));

    float sm = 0.f;
#pragma unroll
    for (int m = 0; m < NCH; ++m)
#pragma unroll
      for (int u = 0; u < 6; ++u) {
        int cc = m * CJ + l + 16 * u;
        int c  = cc - o;
        int j  = jb + cc;
        bool ok = (c >= 0) & (c <= 2 * WI) & (j >= 0) & (j < S_LEN);
        float e = ok ? __expf(acc[m][r][u] - mx) : 0.f;
        acc[m][r][u] = e;
        sm += e;
      }
#pragma unroll
    for (int off = 1; off < 16; off <<= 1)
      sm += __shfl_xor(sm, off, 64);
    const float inv = 1.0f / sm;        // sm > 0: diagonal always in-band

    float* orow = out + (((size_t)(b * S_LEN + i) * NHEAD) + hh) * NC;
#pragma unroll
    for (int m = 0; m < NCH; ++m)
#pragma unroll
      for (int u = 0; u < 6; ++u) {
        int cc = m * CJ + l + 16 * u;
        int c  = cc - o;
        int j  = jb + cc;
        if (c >= 0 && c <= 2 * WI) {
          float val = (j >= 0 && j < S_LEN) ? acc[m][r][u] * inv : 0.f;
          orow[c] = val;               // 16 consecutive lanes -> contiguous c
        }
      }
  }
}

extern "C" void kernel_launch(void* const* d_in, const int* in_sizes, int n_in,
                              void* d_out, int out_size, void* d_ws, size_t ws_size,
                              hipStream_t stream) {
  const float* x = (const float*)d_in[0];
  float* out = (float*)d_out;
  dim3 grid(S_LEN / TI, 32);   // 64 row-tiles x 32 head-groups = 2048 blocks
  sliding_attn_kernel<<<grid, 256, 0, stream>>>(x, out);
}

// Round 2
// 373.767 us; speedup vs baseline: 1.2146x; 1.2146x over previous
//
#include <hip/hip_runtime.h>
#include <math.h>

// B=2, H=16, S=4096, D=64, W=256. Output (2,4096,16,513) fp32.
#define S_LEN 4096
#define NHEAD 16
#define WI    256
#define NC    513
#define TI    64        // query rows per block
#define CK    96        // keys per LDS chunk
#define NCH   6         // 6*96 = 576 = TI + 2*WI
#define NT    36        // key tiles of 16 across the 576 span
#define KSTR  72        // LDS row stride in bf16 elems (pad 64->72: b128 frag reads 2-way = free)

typedef __attribute__((ext_vector_type(8))) short short8;   // 8 bf16 = 4 VGPRs
typedef __attribute__((ext_vector_type(4))) float floatx4;  // MFMA C/D

// split fp32 -> bf16 hi (bit-truncate, exact residual) + bf16 lo (RN of residual)
static __device__ __forceinline__ unsigned short f2bf_rn(float f) {
  unsigned int u = __float_as_uint(f);
  u += 0x7FFFu + ((u >> 16) & 1u);
  return (unsigned short)(u >> 16);
}

__global__ __launch_bounds__(256, 2)
void sliding_attn_mfma(const float* __restrict__ x, float* __restrict__ out) {
  const int t    = threadIdx.x;
  const int p    = blockIdx.y;        // 0..31 head-group
  const int i0   = blockIdx.x * TI;
  const int b    = p >> 4;
  const int hh   = p & 15;
  const int jb   = i0 - WI;           // first key of the band span
  const int w    = t >> 6;            // wave 0..3 -> query rows 16w..16w+15
  const int quad = (t >> 4) & 3;
  const int n    = t & 15;

  __shared__ unsigned short Qh[TI * KSTR], Ql[TI * KSTR];
  __shared__ unsigned short Kh[CK * KSTR], Kl[CK * KSTR];

  // ---- stage Q (64 rows x 64 dims), split to hi/lo bf16 ----
#pragma unroll
  for (int k = 0; k < 4; ++k) {
    int qi = t + k * 256;
    int row = qi >> 4, dq = qi & 15;
    int v = i0 + row;
    int hx = v & 15, sx = (hh << 8) + (v >> 4);
    const float4 val = *(const float4*)(x + (((b * NHEAD + hx) * S_LEN + sx) * 64 + dq * 4));
    ushort4 hi, lo;
    unsigned int ux = __float_as_uint(val.x), uy = __float_as_uint(val.y);
    unsigned int uz = __float_as_uint(val.z), uw = __float_as_uint(val.w);
    hi.x = ux >> 16; hi.y = uy >> 16; hi.z = uz >> 16; hi.w = uw >> 16;
    lo.x = f2bf_rn(val.x - __uint_as_float(ux & 0xFFFF0000u));
    lo.y = f2bf_rn(val.y - __uint_as_float(uy & 0xFFFF0000u));
    lo.z = f2bf_rn(val.z - __uint_as_float(uz & 0xFFFF0000u));
    lo.w = f2bf_rn(val.w - __uint_as_float(uw & 0xFFFF0000u));
    *(ushort4*)(Qh + row * KSTR + dq * 4) = hi;
    *(ushort4*)(Ql + row * KSTR + dq * 4) = lo;
  }
  __syncthreads();

  // ---- A fragments (wave-invariant across all chunks): A[m=lane&15][k=quad*8+j] ----
  const int arow = (w * 16 + n) * KSTR + quad * 8;
  const short8 qh0 = *(const short8*)(Qh + arow);
  const short8 qh1 = *(const short8*)(Qh + arow + 32);
  const short8 ql0 = *(const short8*)(Ql + arow);
  const short8 ql1 = *(const short8*)(Ql + arow + 32);

  floatx4 acc[NT];
#pragma unroll
  for (int jt = 0; jt < NT; ++jt) acc[jt] = (floatx4){0.f, 0.f, 0.f, 0.f};

  // ---- main loop over 6 K-chunks of 96 keys ----
#pragma unroll
  for (int m = 0; m < NCH; ++m) {
    if (m) __syncthreads();          // previous chunk consumed
    // stage K chunk: 96 rows x 64 dims
#pragma unroll
    for (int k = 0; k < 6; ++k) {
      int qi = t + k * 256;
      int rr = qi >> 4, dq = qi & 15;
      int v = jb + m * CK + rr;
      float4 val = make_float4(0.f, 0.f, 0.f, 0.f);
      if (v >= 0 && v < S_LEN) {
        int hx = v & 15, sx = (hh << 8) + (v >> 4);
        val = *(const float4*)(x + (((b * NHEAD + hx) * S_LEN + sx) * 64 + dq * 4));
      }
      ushort4 hi, lo;
      unsigned int ux = __float_as_uint(val.x), uy = __float_as_uint(val.y);
      unsigned int uz = __float_as_uint(val.z), uw = __float_as_uint(val.w);
      hi.x = ux >> 16; hi.y = uy >> 16; hi.z = uz >> 16; hi.w = uw >> 16;
      lo.x = f2bf_rn(val.x - __uint_as_float(ux & 0xFFFF0000u));
      lo.y = f2bf_rn(val.y - __uint_as_float(uy & 0xFFFF0000u));
      lo.z = f2bf_rn(val.z - __uint_as_float(uz & 0xFFFF0000u));
      lo.w = f2bf_rn(val.w - __uint_as_float(uw & 0xFFFF0000u));
      *(ushort4*)(Kh + rr * KSTR + dq * 4) = hi;
      *(ushort4*)(Kl + rr * KSTR + dq * 4) = lo;
    }
    __syncthreads();

    // compute: 6 key-tiles x 2 K-steps x (hh + hl + lh)
#pragma unroll
    for (int u = 0; u < 6; ++u) {
      const int jt = m * 6 + u;
      const int kbase = (u * 16 + n) * KSTR + quad * 8;
      const short8 bh0 = *(const short8*)(Kh + kbase);
      const short8 bh1 = *(const short8*)(Kh + kbase + 32);
      const short8 bl0 = *(const short8*)(Kl + kbase);
      const short8 bl1 = *(const short8*)(Kl + kbase + 32);
      floatx4 c = acc[jt];
      c = __builtin_amdgcn_mfma_f32_16x16x32_bf16(ql0, bh0, c, 0, 0, 0);
      c = __builtin_amdgcn_mfma_f32_16x16x32_bf16(qh0, bl0, c, 0, 0, 0);
      c = __builtin_amdgcn_mfma_f32_16x16x32_bf16(qh0, bh0, c, 0, 0, 0);
      c = __builtin_amdgcn_mfma_f32_16x16x32_bf16(ql1, bh1, c, 0, 0, 0);
      c = __builtin_amdgcn_mfma_f32_16x16x32_bf16(qh1, bl1, c, 0, 0, 0);
      c = __builtin_amdgcn_mfma_f32_16x16x32_bf16(qh1, bh1, c, 0, 0, 0);
      acc[jt] = c;
    }
  }

  // ---- softmax + write. D layout: row = quad*4+reg (query), col = n (key in tile) ----
#pragma unroll
  for (int reg = 0; reg < 4; ++reg) {
    const int o = w * 16 + quad * 4 + reg;   // row offset in tile, 0..63
    const int i = i0 + o;

    float mx = -INFINITY;
#pragma unroll
    for (int jt = 0; jt < NT; ++jt) {
      int cc = jt * 16 + n;
      int c = cc - o;
      int j = jb + cc;
      bool ok = (c >= 0) & (c <= 2 * WI) & (j >= 0) & (j < S_LEN);
      if (ok) mx = fmaxf(mx, acc[jt][reg]);
    }
#pragma unroll
    for (int off = 1; off < 16; off <<= 1)
      mx = fmaxf(mx, __shfl_xor(mx, off, 64));

    float sm = 0.f;
    float e[NT];
#pragma unroll
    for (int jt = 0; jt < NT; ++jt) {
      int cc = jt * 16 + n;
      int c = cc - o;
      int j = jb + cc;
      bool ok = (c >= 0) & (c <= 2 * WI) & (j >= 0) & (j < S_LEN);
      e[jt] = ok ? __expf(acc[jt][reg] - mx) : 0.f;
      sm += e[jt];
    }
#pragma unroll
    for (int off = 1; off < 16; off <<= 1)
      sm += __shfl_xor(sm, off, 64);
    const float inv = 1.0f / sm;   // diagonal always in-band -> sm > 0

    float* orow = out + (((size_t)(b * S_LEN + i) * NHEAD) + hh) * NC;
#pragma unroll
    for (int jt = 0; jt < NT; ++jt) {
      int cc = jt * 16 + n;
      int c = cc - o;
      if (c >= 0 && c <= 2 * WI) orow[c] = e[jt] * inv;
    }
  }
}

extern "C" void kernel_launch(void* const* d_in, const int* in_sizes, int n_in,
                              void* d_out, int out_size, void* d_ws, size_t ws_size,
                              hipStream_t stream) {
  const float* x = (const float*)d_in[0];
  float* out = (float*)d_out;
  dim3 grid(S_LEN / TI, 32);
  sliding_attn_mfma<<<grid, 256, 0, stream>>>(x, out);
}

// Round 3
// 335.991 us; speedup vs baseline: 1.3512x; 1.1124x over previous
//
#include <hip/hip_runtime.h>
#include <math.h>

// B=2, H=16, S=4096, D=64, W=256. Output (2,4096,16,513) fp32.
#define S_LEN 4096
#define NHEAD 16
#define WI    256
#define NC    513
#define TI    64        // query rows per block
#define CK    96        // keys per LDS chunk
#define NCH   6         // 6*96 = 576 = TI + 2*WI
#define NT    36        // key tiles of 16 across the 576 span
#define KSTR  72        // LDS row stride in bf16 elems (pad 64->72; measured conflict-free)
#define PV    (S_LEN * 64)   // elems per p-slice of qr-layout

typedef __attribute__((ext_vector_type(8))) short short8;   // 8 bf16 = 4 VGPRs
typedef __attribute__((ext_vector_type(4))) float floatx4;  // MFMA C/D

static __device__ __forceinline__ unsigned short f2bf_rn(float f) {
  unsigned int u = __float_as_uint(f);
  u += 0x7FFFu + ((u >> 16) & 1u);
  return (unsigned short)(u >> 16);
}

// ---- kernel 1: split fp32 x -> hi/lo bf16, permuted to qr layout (p, v, d) ----
// qr[p, v, d] = x[b = p>>4, h = v&15, s = (p&15)*256 + (v>>4), d]
__global__ __launch_bounds__(256)
void split_kernel(const float* __restrict__ x,
                  unsigned short* __restrict__ xh,
                  unsigned short* __restrict__ xl) {
  const int idx = blockIdx.x * 256 + threadIdx.x;   // float4 unit
  const float4 val = ((const float4*)x)[idx];
  const int d4  = idx & 15;
  const int row = idx >> 4;            // (b*16 + h)*4096 + s
  const int s = row & 4095;
  const int h = (row >> 12) & 15;
  const int b = row >> 16;
  const int p = (b << 4) + (s >> 8);
  const int v = ((s & 255) << 4) + h;
  const size_t off = (size_t)p * PV + v * 64 + d4 * 4;
  const unsigned int ux = __float_as_uint(val.x), uy = __float_as_uint(val.y);
  const unsigned int uz = __float_as_uint(val.z), uw = __float_as_uint(val.w);
  ushort4 hi, lo;
  hi.x = ux >> 16; hi.y = uy >> 16; hi.z = uz >> 16; hi.w = uw >> 16;
  lo.x = f2bf_rn(val.x - __uint_as_float(ux & 0xFFFF0000u));
  lo.y = f2bf_rn(val.y - __uint_as_float(uy & 0xFFFF0000u));
  lo.z = f2bf_rn(val.z - __uint_as_float(uz & 0xFFFF0000u));
  lo.w = f2bf_rn(val.w - __uint_as_float(uw & 0xFFFF0000u));
  *(ushort4*)(xh + off) = hi;
  *(ushort4*)(xl + off) = lo;
}

// ---- kernel 2: banded scores + softmax ----
__global__ __launch_bounds__(256, 2)
void attn_kernel(const unsigned short* __restrict__ xh,
                 const unsigned short* __restrict__ xl,
                 float* __restrict__ out) {
  const int t  = threadIdx.x;
  const int id = blockIdx.x;
  // XCD swizzle: blocks with id%8 == c handle tiles [8c, 8c+8) for each p
  const int p    = id >> 6;
  const int r6   = id & 63;
  const int tile = ((r6 & 7) << 3) | (r6 >> 3);
  const int i0   = tile * TI;
  const int b    = p >> 4;
  const int hh   = p & 15;
  const int jb   = i0 - WI;
  const int w    = t >> 6;
  const int quad = (t >> 4) & 3;
  const int n    = t & 15;

  __shared__ unsigned short Qh[TI * KSTR], Ql[TI * KSTR];
  __shared__ unsigned short Kh[CK * KSTR], Kl[CK * KSTR];

  const unsigned short* ph = xh + (size_t)p * PV;
  const unsigned short* pl = xl + (size_t)p * PV;

#define LOAD_CHUNK(mm, dsth, dstl)                                      \
  { _Pragma("unroll")                                                   \
    for (int k = 0; k < 3; ++k) {                                       \
      const int u = t + (k << 8);                                       \
      const int row = u >> 3, col = (u & 7) << 3;                       \
      const int v = jb + (mm) * CK + row;                               \
      short8 zh = {0,0,0,0,0,0,0,0}, zl = {0,0,0,0,0,0,0,0};            \
      if (v >= 0 && v < S_LEN) {                                        \
        zh = *(const short8*)(ph + (size_t)v * 64 + col);               \
        zl = *(const short8*)(pl + (size_t)v * 64 + col);               \
      }                                                                 \
      (dsth)[k] = zh; (dstl)[k] = zl;                                   \
    } }

#define WRITE_CHUNK(srch, srcl)                                         \
  { _Pragma("unroll")                                                   \
    for (int k = 0; k < 3; ++k) {                                       \
      const int u = t + (k << 8);                                       \
      const int row = u >> 3, col = (u & 7) << 3;                       \
      *(short8*)(Kh + row * KSTR + col) = (srch)[k];                    \
      *(short8*)(Kl + row * KSTR + col) = (srcl)[k];                    \
    } }

  // ---- stage Q (rows i0..i0+63 are contiguous in qr layout) ----
  short8 qbh[2], qbl[2];
#pragma unroll
  for (int k = 0; k < 2; ++k) {
    const int u = t + (k << 8);
    const int row = u >> 3, col = (u & 7) << 3;
    qbh[k] = *(const short8*)(ph + (size_t)(i0 + row) * 64 + col);
    qbl[k] = *(const short8*)(pl + (size_t)(i0 + row) * 64 + col);
  }
  // prefetch K chunk 0 while Q stores go to LDS
  short8 pfh[2][3], pfl[2][3];
  LOAD_CHUNK(0, pfh[0], pfl[0]);
#pragma unroll
  for (int k = 0; k < 2; ++k) {
    const int u = t + (k << 8);
    const int row = u >> 3, col = (u & 7) << 3;
    *(short8*)(Qh + row * KSTR + col) = qbh[k];
    *(short8*)(Ql + row * KSTR + col) = qbl[k];
  }
  __syncthreads();

  // ---- A fragments (wave-invariant): A[m = lane&15][k = quad*8 + j] ----
  const int arow = (w * 16 + n) * KSTR + quad * 8;
  const short8 qh0 = *(const short8*)(Qh + arow);
  const short8 qh1 = *(const short8*)(Qh + arow + 32);
  const short8 ql0 = *(const short8*)(Ql + arow);
  const short8 ql1 = *(const short8*)(Ql + arow + 32);

  floatx4 acc[NT];
#pragma unroll
  for (int jt = 0; jt < NT; ++jt) acc[jt] = (floatx4){0.f, 0.f, 0.f, 0.f};

  // ---- main loop: ping-pong register prefetch, prefetch overlaps MFMA ----
#pragma unroll
  for (int m = 0; m < NCH; ++m) {
    WRITE_CHUNK(pfh[m & 1], pfl[m & 1]);
    __syncthreads();
    if (m < NCH - 1) LOAD_CHUNK(m + 1, pfh[(m + 1) & 1], pfl[(m + 1) & 1]);
#pragma unroll
    for (int u = 0; u < 6; ++u) {
      const int jt = m * 6 + u;
      const int kbase = (u * 16 + n) * KSTR + quad * 8;
      const short8 bh0 = *(const short8*)(Kh + kbase);
      const short8 bh1 = *(const short8*)(Kh + kbase + 32);
      const short8 bl0 = *(const short8*)(Kl + kbase);
      const short8 bl1 = *(const short8*)(Kl + kbase + 32);
      floatx4 c = acc[jt];
      c = __builtin_amdgcn_mfma_f32_16x16x32_bf16(ql0, bh0, c, 0, 0, 0);
      c = __builtin_amdgcn_mfma_f32_16x16x32_bf16(qh0, bl0, c, 0, 0, 0);
      c = __builtin_amdgcn_mfma_f32_16x16x32_bf16(qh0, bh0, c, 0, 0, 0);
      c = __builtin_amdgcn_mfma_f32_16x16x32_bf16(ql1, bh1, c, 0, 0, 0);
      c = __builtin_amdgcn_mfma_f32_16x16x32_bf16(qh1, bl1, c, 0, 0, 0);
      c = __builtin_amdgcn_mfma_f32_16x16x32_bf16(qh1, bh1, c, 0, 0, 0);
      acc[jt] = c;
    }
    if (m < NCH - 1) __syncthreads();
  }

  // ---- softmax + store. D layout: row = quad*4+reg, col = n ----
#pragma unroll
  for (int reg = 0; reg < 4; ++reg) {
    const int o = w * 16 + quad * 4 + reg;
    const int i = i0 + o;

    // Unmasked max: over-estimate is softmax-safe (extra entries are real
    // dots or 0; ratios unchanged, no overflow since all exps become <= 1).
    float mx = acc[0][reg];
#pragma unroll
    for (int jt = 1; jt < NT; ++jt) mx = fmaxf(mx, acc[jt][reg]);
#pragma unroll
    for (int off = 1; off < 16; off <<= 1)
      mx = fmaxf(mx, __shfl_xor(mx, off, 64));

    // Valid-tile interval per lane: c = 16*jt + n - o in [0,512],
    // j = jb + 16*jt + n in [0,S)  ->  jt in [lo, hi]
    const int A    = o - n;
    const int lo_c = (A + 15) >> 4;
    const int hi_c = (A + 512) >> 4;
    const int lo_j = (15 - jb - n) >> 4;
    const int hi_j = (4095 - jb - n) >> 4;
    const int lo   = max(lo_c, lo_j);
    const unsigned rng = (unsigned)(min(hi_c, hi_j) - lo);

    float sm = 0.f;
#pragma unroll
    for (int jt = 0; jt < NT; ++jt) {
      const bool ok = (unsigned)(jt - lo) <= rng;
      float e = __expf(acc[jt][reg] - mx);   // <= 1, garbage-safe
      e = ok ? e : 0.f;
      acc[jt][reg] = e;
      sm += e;
    }
#pragma unroll
    for (int off = 1; off < 16; off <<= 1)
      sm += __shfl_xor(sm, off, 64);
    const float inv = 1.0f / sm;             // diagonal always in-band

    float* pb = out + (((size_t)(b * S_LEN + i) * NHEAD) + hh) * NC + (n - o);
#pragma unroll
    for (int jt = 0; jt < NT; ++jt) {
      if ((unsigned)(jt - lo) <= rng) pb[jt << 4] = acc[jt][reg] * inv;
    }
  }
#undef LOAD_CHUNK
#undef WRITE_CHUNK
}

extern "C" void kernel_launch(void* const* d_in, const int* in_sizes, int n_in,
                              void* d_out, int out_size, void* d_ws, size_t ws_size,
                              hipStream_t stream) {
  const float* x = (const float*)d_in[0];
  float* out = (float*)d_out;
  unsigned short* xh = (unsigned short*)d_ws;
  unsigned short* xl = xh + (size_t)32 * PV;   // 8.39M elems each (33.6 MB total)

  split_kernel<<<(32 * PV / 4) / 256, 256, 0, stream>>>(x, xh, xl);
  attn_kernel<<<2048, 256, 0, stream>>>(xh, xl, out);
}